// Round 15
// baseline (147.485 us; speedup 1.0000x reference)
//
#include <hip/hip_runtime.h>

// CAPBlock r15: r14 (146.4us best) with bag-conversion FOLDED into proj
// staging — proj reads bag f32 directly (reg-stage: issue-early f32 loads,
// cvt+swizzled ds_write after compute, T14 pattern), killing convert's 48MB
// bag pass. prep converts only weights+query (4MB) + mask detect.
// attn/combine BYTE-IDENTICAL to r12/r13/r14 (frozen at 67.3us).
// Shapes: B=4, Q=256, K=4096, Ein=E=512, H=8, DH=64.
//
// ws (~52MB): mflag 16B | qh u16 1MB | kh u16 16.8MB | vT f16 16.8MB | REGION
//   REGION phase1: wqk_h 0.5 | wv_h 0.5 | query_h 1.0   (prep -> proj)
//   REGION phase2: po 16.8 | ps 0.5                      (attn -> combine)

#define BATCH 4
#define QLEN 256
#define KLEN 4096
#define EDIM 512
#define NHEAD 8
#define DHEAD 64
#define NC 16

#define ALPHA 0.21153831f
#define C2EXP 15.276518f
#define QSCALE 16384.0f
#define SADSCALE 6.103515625e-5f  // 1/16384

typedef float f32x4 __attribute__((ext_vector_type(4)));
typedef _Float16 f16x8 __attribute__((ext_vector_type(8)));
typedef _Float16 f16x4 __attribute__((ext_vector_type(4)));
typedef unsigned int u32x4 __attribute__((ext_vector_type(4)));

#define GLDS16(g, l)                                                     \
    __builtin_amdgcn_global_load_lds(                                    \
        (const __attribute__((address_space(1))) unsigned int*)(g),      \
        (__attribute__((address_space(3))) unsigned int*)(l), 16, 0, 0)

__device__ __forceinline__ unsigned short quant_u16(float x) {
    const float y = fminf(fmaxf(x * QSCALE + 32768.5f, 0.f), 65535.f);
    return (unsigned short)y;
}

// -------- prep: f32 -> fp16 for Wqk, Wv, query (4MB) + mask detect ----------
__global__ __launch_bounds__(256) void prep_kernel(
    const float* __restrict__ wqk, const float* __restrict__ wv,
    const float* __restrict__ query, const unsigned char* __restrict__ mask,
    _Float16* __restrict__ wqk_h, _Float16* __restrict__ wv_h,
    _Float16* __restrict__ query_h, int* __restrict__ flag) {
    const int NW = (EDIM * EDIM) / 4;           // float4 counts
    const int NQ = (BATCH * QLEN * EDIM) / 4;
    for (int i = blockIdx.x * 256 + threadIdx.x; i < 2 * NW + NQ;
         i += gridDim.x * 256) {
        const float4* s;
        _Float16* d;
        int j;
        if (i < NW) { s = (const float4*)wqk; d = wqk_h; j = i; }
        else if (i < 2 * NW) { s = (const float4*)wv; d = wv_h; j = i - NW; }
        else { s = (const float4*)query; d = query_h; j = i - 2 * NW; }
        const float4 v = s[j];
        f16x4 h;
        h[0] = (_Float16)v.x; h[1] = (_Float16)v.y;
        h[2] = (_Float16)v.z; h[3] = (_Float16)v.w;
        *(f16x4*)&d[(size_t)j * 4] = h;
    }
    // mask dtype detect (bool-as-byte vs int32); deterministic per input.
    if (blockIdx.x == 0) {
        __shared__ int nz;
        if (threadIdx.x == 0) nz = 0;
        __syncthreads();
        int acc = 0;
        for (int i = threadIdx.x; i < BATCH * KLEN; i += 256)
            if (i & 3) acc |= mask[i];
        if (acc) atomicOr(&nz, 1);
        __syncthreads();
        if (threadIdx.x == 0) *flag = (nz == 0) ? 1 : 0;  // 1 => int32
    }
}

// -------- unified projection GEMM: dbuf, A from f32 bag (reg-staged) --------
// grid (136, 8): by = A m-tile (XCD = by%8 -> the 8 bx-blocks of one A-tile
// share an XCD-L2), bx = n-path (<4: Wqk -> kh/qh, >=4: Wv -> vT).
// A-staging (bag path): f32 loads for t+1 issued BEFORE compute(t); cvt +
// swizzled ds_write AFTER compute (T14 issue-early/write-late). query path
// and B stay glds fp16. 128x128 tile, BK=64, 4 waves, one barrier/step.
__global__ __launch_bounds__(256, 2) void proj_gemm_kernel(
    const float* __restrict__ bagf, const _Float16* __restrict__ query_h,
    const _Float16* __restrict__ wqk_h, const _Float16* __restrict__ wv_h,
    const float* __restrict__ bqk, const float* __restrict__ bv,
    const float* __restrict__ diag, unsigned short* __restrict__ kh,
    unsigned short* __restrict__ qh, _Float16* __restrict__ vT) {
    __shared__ _Float16 Ah[2][128][64];
    __shared__ _Float16 Bh[2][128][64];

    const int tid = threadIdx.x;
    const int lane = tid & 63, wid = tid >> 6;
    const int wm = wid >> 1, wn = wid & 1;
    const int l15 = lane & 15, kg4 = lane >> 4;
    const int lrow = lane >> 3, lu = lane & 7;
    const int by = blockIdx.x;         // A m-tile (XCD-locality axis)
    const int bx = blockIdx.y;         // n-path
    const int isV = bx >> 2;
    const int isQ = by >> 7;           // query m-tiles (Wqk path only)
    if (isV && isQ) return;            // uniform across block: safe
    const _Float16* __restrict__ W = isV ? wv_h : wqk_h;
    const int n0 = (bx & 3) * 128;
    const int m0 = (isQ ? (by - 128) : by) * 128;  // local to A source
    const int srcu = (lu ^ lrow) * 8;  // pre-swizzled source unit (halves)

    f32x4 acc[4][4];
#pragma unroll
    for (int i = 0; i < 4; ++i)
#pragma unroll
        for (int j = 0; j < 4; ++j) acc[i][j] = (f32x4)0.f;

    // ---- prologue: stage tile 0 ----
#pragma unroll
    for (int i = 0; i < 4; ++i) {
        const int rb = wid * 32 + i * 8;
        GLDS16(&W[(size_t)(n0 + rb + lrow) * EDIM + srcu], &Bh[0][rb][0]);
    }
    if (isQ) {
#pragma unroll
        for (int i = 0; i < 4; ++i) {
            const int rb = wid * 32 + i * 8;
            GLDS16(&query_h[(size_t)(m0 + rb + lrow) * EDIM + srcu], &Ah[0][rb][0]);
        }
    } else {
#pragma unroll
        for (int i = 0; i < 4; ++i) {
            const int idx = i * 256 + tid, row = idx >> 3, u = idx & 7;
            const float* s = &bagf[(size_t)(m0 + row) * EDIM + u * 8];
            const float4 f0 = *(const float4*)s, f1 = *(const float4*)(s + 4);
            f16x8 hv;
            hv[0] = (_Float16)f0.x; hv[1] = (_Float16)f0.y;
            hv[2] = (_Float16)f0.z; hv[3] = (_Float16)f0.w;
            hv[4] = (_Float16)f1.x; hv[5] = (_Float16)f1.y;
            hv[6] = (_Float16)f1.z; hv[7] = (_Float16)f1.w;
            *(f16x8*)&Ah[0][row][(u ^ (row & 7)) * 8] = hv;
        }
    }
    __syncthreads();  // drains glds (vmcnt) + ds_writes (lgkm)

    float4 areg[8];
    for (int t = 0; t < 8; ++t) {
        const int cur = t & 1;
        if (t < 7) {  // issue next tile's loads FIRST (hide under compute)
            const int k1 = (t + 1) * 64;
#pragma unroll
            for (int i = 0; i < 4; ++i) {
                const int rb = wid * 32 + i * 8;
                GLDS16(&W[(size_t)(n0 + rb + lrow) * EDIM + k1 + srcu],
                       &Bh[cur ^ 1][rb][0]);
            }
            if (isQ) {
#pragma unroll
                for (int i = 0; i < 4; ++i) {
                    const int rb = wid * 32 + i * 8;
                    GLDS16(&query_h[(size_t)(m0 + rb + lrow) * EDIM + k1 + srcu],
                           &Ah[cur ^ 1][rb][0]);
                }
            } else {
#pragma unroll
                for (int i = 0; i < 4; ++i) {
                    const int idx = i * 256 + tid, row = idx >> 3, u = idx & 7;
                    const float* s = &bagf[(size_t)(m0 + row) * EDIM + k1 + u * 8];
                    areg[i * 2] = *(const float4*)s;
                    areg[i * 2 + 1] = *(const float4*)(s + 4);
                }
            }
        }
        // ---- compute tile t ----
#pragma unroll
        for (int s = 0; s < 2; ++s) {
            f16x8 a8[4], b8[4];
#pragma unroll
            for (int mf = 0; mf < 4; ++mf) {
                const int row = wm * 64 + mf * 16 + l15;
                a8[mf] = *(const f16x8*)&Ah[cur][row][((s * 4 + kg4) ^ (row & 7)) * 8];
            }
#pragma unroll
            for (int nf = 0; nf < 4; ++nf) {
                const int row = wn * 64 + nf * 16 + l15;
                b8[nf] = *(const f16x8*)&Bh[cur][row][((s * 4 + kg4) ^ (row & 7)) * 8];
            }
#pragma unroll
            for (int nf = 0; nf < 4; ++nf)
#pragma unroll
                for (int mf = 0; mf < 4; ++mf)
                    acc[mf][nf] = __builtin_amdgcn_mfma_f32_16x16x32_f16(
                        a8[mf], b8[nf], acc[mf][nf], 0, 0, 0);
        }
        // ---- A write-late (bag path): cvt regs -> swizzled LDS ----
        if (t < 7 && !isQ) {
#pragma unroll
            for (int i = 0; i < 4; ++i) {
                const int idx = i * 256 + tid, row = idx >> 3, u = idx & 7;
                const float* p0 = (const float*)&areg[i * 2];
                const float* p1 = (const float*)&areg[i * 2 + 1];
                f16x8 hv;
#pragma unroll
                for (int j = 0; j < 4; ++j) {
                    hv[j] = (_Float16)p0[j];
                    hv[4 + j] = (_Float16)p1[j];
                }
                *(f16x8*)&Ah[cur ^ 1][row][(u ^ (row & 7)) * 8] = hv;
            }
        }
        __syncthreads();  // drains glds + ds_writes; orders buffer reuse
    }

#pragma unroll
    for (int nf = 0; nf < 4; ++nf) {
        const int n = n0 + wn * 64 + nf * 16 + l15;
        if (!isV) {
            const float bi = bqk[n];
            const float sc = diag[n] * ALPHA;
            unsigned short* __restrict__ dst = isQ ? qh : kh;
#pragma unroll
            for (int mf = 0; mf < 4; ++mf)
#pragma unroll
                for (int rr = 0; rr < 4; ++rr) {
                    const int m = m0 + wm * 64 + mf * 16 + kg4 * 4 + rr;
                    dst[(size_t)m * EDIM + n] = quant_u16((acc[mf][nf][rr] + bi) * sc);
                }
        } else {
            const float bi = bv[n];
#pragma unroll
            for (int mf = 0; mf < 4; ++mf) {
                const int kb = m0 + wm * 64 + mf * 16 + kg4 * 4;
                const int bb = kb >> 12, kk = kb & (KLEN - 1);
                f16x4 pk;
#pragma unroll
                for (int rr = 0; rr < 4; ++rr) pk[rr] = (_Float16)(acc[mf][nf][rr] + bi);
                *(f16x4*)&vT[((size_t)(bb * NHEAD + (n >> 6)) * DHEAD + (n & 63)) * KLEN + kk] = pk;
            }
        }
    }
}

// -------- L1-distance attention: sad_u16 + MFMA PV (r12 EXACT, frozen) ------
// grid (NC*2, H, B) = 1024 blocks; block = 4 waves x 32 q; chunk 256 k.
__global__ __launch_bounds__(256, 4) void attn_mfma_kernel(
    const unsigned short* __restrict__ qh, const unsigned short* __restrict__ kh,
    const _Float16* __restrict__ vT, const void* __restrict__ mask,
    const float* __restrict__ rel, const int* __restrict__ mflag,
    unsigned short* __restrict__ po, float* __restrict__ ps) {
    __shared__ union SM {
        struct { unsigned short K[64][64]; _Float16 V[64][64]; _Float16 M[64]; } t;
        _Float16 osm[64][136];  // epilogue d x q transpose buffer
    } sm;
    __shared__ u32x4 qsm[4][8][32];  // [wave][16B-unit][q-row], u16 data

    const int tid = threadIdx.x;
    const int lane = tid & 63, wid = tid >> 6;
    const int l15 = lane & 15, kg4 = lane >> 4;
    const int lrow = lane >> 3, lu = lane & 7;
    const int c = blockIdx.x & (NC - 1), qhi = blockIdx.x / NC;
    const int h = blockIdx.y, b = blockIdx.z;
    const int qbase = qhi * 128 + wid * 32;
    const int mfl = *mflag;
    const float adn = rel[b * NHEAD + h];

    // stage this wave's 32 q rows: [c8][row] 16B units
#pragma unroll
    for (int s = 0; s < 2; ++s) {
        const size_t qrow = (size_t)(b * QLEN + qbase + s * 16 + l15) * EDIM + h * DHEAD;
#pragma unroll
        for (int cc = 0; cc < 2; ++cc) {
            const int c8 = kg4 * 2 + cc;
            qsm[wid][c8][s * 16 + l15] = *(const u32x4*)&qh[qrow + c8 * 8];
        }
    }
    // no barrier: each wave reads only its own qsm region (lgkm-ordered)

    f32x4 acc[2][4];
#pragma unroll
    for (int s = 0; s < 2; ++s)
#pragma unroll
        for (int nf = 0; nf < 4; ++nf) acc[s][nf] = (f32x4)0.f;
    float sacc[2] = {0.f, 0.f};

    for (int t = 0; t < (KLEN / NC) / 64; ++t) {
        const int kbase = c * (KLEN / NC) + t * 64;
        __syncthreads();  // previous tile fully consumed
#pragma unroll
        for (int i = 0; i < 2; ++i) {
            const int rb = (i * 4 + wid) * 8;
            const int krow = rb + lrow;
            const int su_k = (lu ^ (i * 4 + wid)) * 8;   // K: unit^rowgroup
            GLDS16(&kh[(size_t)(b * KLEN + kbase + krow) * EDIM + h * DHEAD + su_k],
                   &sm.t.K[rb][0]);
            const int su_v = (lu ^ lrow) * 8;            // V: unit^(d&7)
            GLDS16(&vT[(size_t)((b * NHEAD + h) * DHEAD + krow) * KLEN + kbase + su_v],
                   &sm.t.V[rb][0]);
        }
        if (tid < 64) {
            const int kg = b * KLEN + kbase + tid;
            const int mv = mfl ? ((const int*)mask)[kg]
                               : (int)((const unsigned char*)mask)[kg];
            sm.t.M[tid] = mv ? (_Float16)1.f : (_Float16)0.f;
        }
        __syncthreads();  // drains glds (vmcnt) + mask writes

        unsigned dist[2][16];
#pragma unroll
        for (int s = 0; s < 2; ++s)
#pragma unroll
            for (int j = 0; j < 16; ++j) dist[s][j] = 0u;

#pragma unroll
        for (int c8 = 0; c8 < 8; ++c8) {
            u32x4 qv[2];
            qv[0] = qsm[wid][c8][l15];
            qv[1] = qsm[wid][c8][16 + l15];
#pragma unroll
            for (int hf = 0; hf < 2; ++hf) {
                const int unit = (c8 ^ (hf * 4 + kg4)) * 8;
#pragma unroll
                for (int j = 0; j < 8; ++j) {
                    const int kk = hf * 32 + kg4 * 8 + j;
                    const u32x4 ku = *(const u32x4*)&sm.t.K[kk][unit];
#pragma unroll
                    for (int p = 0; p < 4; ++p) {
                        dist[0][hf * 8 + j] = __builtin_amdgcn_sad_u16(
                            ku[p], qv[0][p], dist[0][hf * 8 + j]);
                        dist[1][hf * 8 + j] = __builtin_amdgcn_sad_u16(
                            ku[p], qv[1][p], dist[1][hf * 8 + j]);
                    }
                }
            }
        }

#pragma unroll
        for (int hf = 0; hf < 2; ++hf) {
            const f16x8 mv8 = *(const f16x8*)&sm.t.M[hf * 32 + kg4 * 8];
            unsigned pw[2][4];
#pragma unroll
            for (int s = 0; s < 2; ++s) {
                float w[8];
#pragma unroll
                for (int j = 0; j < 8; ++j) {
                    // e = mask * 2^(C2 - dist*s); w = e/(e+adn)  (== reference)
                    const float e =
                        exp2f(C2EXP - (float)dist[s][hf * 8 + j] * SADSCALE) * (float)mv8[j];
                    w[j] = e * __builtin_amdgcn_rcpf(e + adn);
                    sacc[s] += w[j];
                }
#pragma unroll
                for (int m2 = 0; m2 < 4; ++m2)
                    pw[s][m2] = __builtin_bit_cast(unsigned,
                        __builtin_amdgcn_cvt_pkrtz(w[2 * m2], w[2 * m2 + 1]));
            }
#pragma unroll
            for (int nf = 0; nf < 4; ++nf) {
                const int vrow = nf * 16 + l15;
                const f16x8 b8 = *(const f16x8*)
                    &sm.t.V[vrow][(((hf * 4 + kg4) ^ (l15 & 7))) * 8];
                union { unsigned u[4]; f16x8 v; } a0, a1;
#pragma unroll
                for (int p = 0; p < 4; ++p) { a0.u[p] = pw[0][p]; a1.u[p] = pw[1][p]; }
                acc[0][nf] = __builtin_amdgcn_mfma_f32_16x16x32_f16(a0.v, b8, acc[0][nf], 0, 0, 0);
                acc[1][nf] = __builtin_amdgcn_mfma_f32_16x16x32_f16(a1.v, b8, acc[1][nf], 0, 0, 0);
            }
        }
    }

#pragma unroll
    for (int s = 0; s < 2; ++s) {
        sacc[s] += __shfl_xor(sacc[s], 16);
        sacc[s] += __shfl_xor(sacc[s], 32);
    }
    const size_t bhc = (size_t)(b * NHEAD + h) * NC + c;
    if (lane < 16) {
#pragma unroll
        for (int s = 0; s < 2; ++s)
            ps[bhc * QLEN + qbase + s * 16 + lane] = sacc[s];
    }

    __syncthreads();  // everyone done with sm.t
#pragma unroll
    for (int s = 0; s < 2; ++s)
#pragma unroll
        for (int nf = 0; nf < 4; ++nf)
#pragma unroll
            for (int rr = 0; rr < 4; ++rr) {
                const int qloc = wid * 32 + s * 16 + kg4 * 4 + rr;
                sm.osm[nf * 16 + l15][qloc] = (_Float16)acc[s][nf][rr];
            }
    __syncthreads();
    {
        const int d = tid >> 2, seg = tid & 3;
        const f16x8* src = (const f16x8*)&sm.osm[d][seg * 32];
        f16x8* dst = (f16x8*)(po + (bhc * 64 + d) * QLEN + qhi * 128 + seg * 32);
#pragma unroll
        for (int i = 0; i < 4; ++i) dst[i] = src[i];
    }
}

// -------- combine partials, normalize, write out ----------------------------
__global__ __launch_bounds__(256) void combine_kernel(
    const unsigned short* __restrict__ po, const float* __restrict__ ps,
    float* __restrict__ out, int nch) {
    const int d4 = blockIdx.x, h = blockIdx.y, b = blockIdx.z;
    const int q = threadIdx.x;
    const int bh = b * NHEAD + h;

    float s = 0.f;
    for (int c = 0; c < nch; ++c)
        s += ps[((size_t)(bh * nch + c)) * QLEN + q];

    float o[4] = {0.f, 0.f, 0.f, 0.f};
    for (int c = 0; c < nch; ++c) {
#pragma unroll
        for (int j = 0; j < 4; ++j) {
            const int d = d4 * 4 + j;
            const unsigned short raw = po[((size_t)((bh * nch + c) * 64 + d)) * QLEN + q];
            o[j] += (float)*(const _Float16*)&raw;
        }
    }
    const float inv = 1.0f / fmaxf(s, 1e-12f);
#pragma unroll
    for (int j = 0; j < 4; ++j)
        out[((size_t)(b * QLEN + q)) * EDIM + h * DHEAD + d4 * 4 + j] = o[j] * inv;
}

extern "C" void kernel_launch(void* const* d_in, const int* in_sizes, int n_in,
                              void* d_out, int out_size, void* d_ws, size_t ws_size,
                              hipStream_t stream) {
    const float* query = (const float*)d_in[0];
    const float* bag   = (const float*)d_in[1];
    const void*  mask  = d_in[2];
    const float* rel   = (const float*)d_in[3];
    const float* Wqk   = (const float*)d_in[4];
    const float* bqk   = (const float*)d_in[5];
    const float* Wv    = (const float*)d_in[6];
    const float* bv    = (const float*)d_in[7];
    const float* diag  = (const float*)d_in[8];
    float* out = (float*)d_out;

    char* wsb = (char*)d_ws;
    int* mflag = (int*)wsb;
    unsigned short* qh = (unsigned short*)(wsb + 16);
    unsigned short* kh = qh + (size_t)BATCH * QLEN * EDIM;
    _Float16* vT = (_Float16*)(kh + (size_t)BATCH * KLEN * EDIM);
    char* region = (char*)(vT + (size_t)BATCH * KLEN * EDIM);
    // phase 1 (pre-attn): converted weights + query
    _Float16* wqk_h = (_Float16*)region;
    _Float16* wv_h = wqk_h + (size_t)EDIM * EDIM;
    _Float16* query_h = wv_h + (size_t)EDIM * EDIM;
    // phase 2 (attn output partials) — overlaps phase 1 (order-safe)
    unsigned short* po = (unsigned short*)region;
    float* psb = (float*)(region + (size_t)BATCH * NHEAD * NC * QLEN * DHEAD * 2);

    prep_kernel<<<512, 256, 0, stream>>>(
        Wqk, Wv, query, (const unsigned char*)mask, wqk_h, wv_h, query_h, mflag);

    // unified dbuf GEMM: A = bag f32 (reg-staged cvt) or query_h (glds);
    // k'/q' = quant_u16((A@Wqk^T+bqk)*diag*alpha); v -> vT fp16.
    proj_gemm_kernel<<<dim3(136, 8), 256, 0, stream>>>(
        bag, query_h, wqk_h, wv_h, bqk, bv, diag, kh, qh, vT);

    attn_mfma_kernel<<<dim3(NC * 2, NHEAD, BATCH), 256, 0, stream>>>(
        qh, kh, vT, mask, rel, mflag, po, psb);

    combine_kernel<<<dim3(16, NHEAD, BATCH), 256, 0, stream>>>(po, psb, out, NC);
}

// Round 16
// 139.957 us; speedup vs baseline: 1.0538x; 1.0538x over previous
//
#include <hip/hip_runtime.h>

// CAPBlock r16: r14 skeleton (146.4us best; r15's bag-fold reverted) with proj
// restructured for OCCUPANCY: 8 waves x 512 thr, wave-tile 64x32 (acc[4][2] =
// 32 regs, was 64) -> ~3 blocks/CU vs 2 waves/SIMD. Single-buffered BK=64,
// 2-barrier glds (m97 shape), XOR swizzle, XCD grid (136,8).
// convert/attn/combine BYTE-IDENTICAL to r14 (attn frozen at 67.3us).
// Shapes: B=4, Q=256, K=4096, Ein=E=512, H=8, DH=64.
//
// ws (53.4MB):
//   mflag 16B | qh u16 1MB | kh u16 16.8MB | vT f16 16.8MB | REGION 18.8MB
//   REGION phase1: bag_h 16.8 | wqk_h 0.5 | wv_h 0.5 | query_h 1.0
//   REGION phase2: po 16.8 | ps 0.5

#define BATCH 4
#define QLEN 256
#define KLEN 4096
#define EDIM 512
#define NHEAD 8
#define DHEAD 64
#define NC 16

#define ALPHA 0.21153831f
#define C2EXP 15.276518f
#define QSCALE 16384.0f
#define SADSCALE 6.103515625e-5f  // 1/16384

typedef float f32x4 __attribute__((ext_vector_type(4)));
typedef _Float16 f16x8 __attribute__((ext_vector_type(8)));
typedef _Float16 f16x4 __attribute__((ext_vector_type(4)));
typedef unsigned int u32x4 __attribute__((ext_vector_type(4)));

#define GLDS16(g, l)                                                     \
    __builtin_amdgcn_global_load_lds(                                    \
        (const __attribute__((address_space(1))) unsigned int*)(g),      \
        (__attribute__((address_space(3))) unsigned int*)(l), 16, 0, 0)

__device__ __forceinline__ unsigned short quant_u16(float x) {
    const float y = fminf(fmaxf(x * QSCALE + 32768.5f, 0.f), 65535.f);
    return (unsigned short)y;
}

// -------- f32 -> fp16 convert (bag, Wqk, Wv, query) + mask detect -----------
__global__ __launch_bounds__(256) void convert_kernel(
    const float* __restrict__ bag, const float* __restrict__ wqk,
    const float* __restrict__ wv, const float* __restrict__ query,
    const unsigned char* __restrict__ mask,
    _Float16* __restrict__ bag_h, _Float16* __restrict__ wqk_h,
    _Float16* __restrict__ wv_h, _Float16* __restrict__ query_h,
    int* __restrict__ flag) {
    const int NB = (BATCH * KLEN * EDIM) / 4;   // float4 counts
    const int NW = (EDIM * EDIM) / 4;
    const int NQ = (BATCH * QLEN * EDIM) / 4;
    for (int i = blockIdx.x * 256 + threadIdx.x; i < NB + 2 * NW + NQ;
         i += gridDim.x * 256) {
        const float4* s;
        _Float16* d;
        int j;
        if (i < NB) { s = (const float4*)bag; d = bag_h; j = i; }
        else if (i < NB + NW) { s = (const float4*)wqk; d = wqk_h; j = i - NB; }
        else if (i < NB + 2 * NW) { s = (const float4*)wv; d = wv_h; j = i - NB - NW; }
        else { s = (const float4*)query; d = query_h; j = i - NB - 2 * NW; }
        const float4 v = s[j];
        f16x4 h;
        h[0] = (_Float16)v.x; h[1] = (_Float16)v.y;
        h[2] = (_Float16)v.z; h[3] = (_Float16)v.w;
        *(f16x4*)&d[(size_t)j * 4] = h;
    }
    // mask dtype detect (bool-as-byte vs int32); deterministic per input.
    if (blockIdx.x == 0) {
        __shared__ int nz;
        if (threadIdx.x == 0) nz = 0;
        __syncthreads();
        int acc = 0;
        for (int i = threadIdx.x; i < BATCH * KLEN; i += 256)
            if (i & 3) acc |= mask[i];
        if (acc) atomicOr(&nz, 1);
        __syncthreads();
        if (threadIdx.x == 0) *flag = (nz == 0) ? 1 : 0;  // 1 => int32
    }
}

// -------- unified projection GEMM: 8-wave, 64x32 wave-tile, 1buf glds -------
// grid (136, 8): by = A m-tile (XCD = by%8 -> same-A blocks share an XCD L2),
// bx = n-path (<4: Wqk -> kh/qh, >=4: Wv -> vT). 512 thr = 8 waves (2m x 4n),
// wave-tile 64x32 -> acc[4][2] (32 regs: occupancy ~3 blocks/CU vs 2 w/SIMD).
// Single-buffered BK=64, 2 barriers/step, glds w/ pre-swizzled source.
__global__ __launch_bounds__(512) void proj_gemm_kernel(
    const _Float16* __restrict__ bag_h, const _Float16* __restrict__ query_h,
    const _Float16* __restrict__ wqk_h, const _Float16* __restrict__ wv_h,
    const float* __restrict__ bqk, const float* __restrict__ bv,
    const float* __restrict__ diag, unsigned short* __restrict__ kh,
    unsigned short* __restrict__ qh, _Float16* __restrict__ vT) {
    __shared__ _Float16 Ah[128][64];
    __shared__ _Float16 Bh[128][64];

    const int tid = threadIdx.x;
    const int lane = tid & 63, wid = tid >> 6;      // 8 waves
    const int wm = wid >> 2, wn = wid & 3;          // 2m x 4n
    const int l15 = lane & 15, kg4 = lane >> 4;
    const int lrow = lane >> 3, lu = lane & 7;
    const int by = blockIdx.x;         // A m-tile (XCD-locality axis)
    const int bx = blockIdx.y;         // n-path
    const int isV = bx >> 2;
    const int isQ = by >> 7;           // query m-tiles (Wqk path only)
    if (isV && isQ) return;            // uniform across block: safe
    const _Float16* __restrict__ W = isV ? wv_h : wqk_h;
    const _Float16* __restrict__ A = isQ ? query_h : bag_h;
    const int n0 = (bx & 3) * 128;
    const int m0 = (isQ ? (by - 128) : by) * 128;  // local to A buffer
    const int srcu = (lu ^ lrow) * 8;  // pre-swizzled source unit (halves)

    f32x4 acc[4][2];
#pragma unroll
    for (int i = 0; i < 4; ++i)
#pragma unroll
        for (int j = 0; j < 2; ++j) acc[i][j] = (f32x4)0.f;

    for (int k0 = 0; k0 < EDIM; k0 += 64) {
        __syncthreads();  // previous tile fully consumed
        // stage: each wave covers 8 rows x 8 units per round; 2 rounds/matrix
#pragma unroll
        for (int i = 0; i < 2; ++i) {
            const int rb = i * 64 + wid * 8;            // wave-uniform row block
            const int row = rb + lrow;                  // lane's source row
            GLDS16(&A[(size_t)(m0 + row) * EDIM + k0 + srcu], &Ah[rb][0]);
            GLDS16(&W[(size_t)(n0 + row) * EDIM + k0 + srcu], &Bh[rb][0]);
        }
        __syncthreads();  // drains glds (vmcnt) before reads

#pragma unroll
        for (int s = 0; s < 2; ++s) {
            f16x8 a8[4], b8[2];
#pragma unroll
            for (int mf = 0; mf < 4; ++mf) {
                const int row = wm * 64 + mf * 16 + l15;
                a8[mf] = *(const f16x8*)&Ah[row][((s * 4 + kg4) ^ (row & 7)) * 8];
            }
#pragma unroll
            for (int nf = 0; nf < 2; ++nf) {
                const int row = wn * 32 + nf * 16 + l15;
                b8[nf] = *(const f16x8*)&Bh[row][((s * 4 + kg4) ^ (row & 7)) * 8];
            }
#pragma unroll
            for (int nf = 0; nf < 2; ++nf)
#pragma unroll
                for (int mf = 0; mf < 4; ++mf)
                    acc[mf][nf] = __builtin_amdgcn_mfma_f32_16x16x32_f16(
                        a8[mf], b8[nf], acc[mf][nf], 0, 0, 0);
        }
    }

#pragma unroll
    for (int nf = 0; nf < 2; ++nf) {
        const int n = n0 + wn * 32 + nf * 16 + l15;
        if (!isV) {
            const float bi = bqk[n];
            const float sc = diag[n] * ALPHA;
            unsigned short* __restrict__ dst = isQ ? qh : kh;
#pragma unroll
            for (int mf = 0; mf < 4; ++mf)
#pragma unroll
                for (int rr = 0; rr < 4; ++rr) {
                    const int m = m0 + wm * 64 + mf * 16 + kg4 * 4 + rr;
                    dst[(size_t)m * EDIM + n] = quant_u16((acc[mf][nf][rr] + bi) * sc);
                }
        } else {
            const float bi = bv[n];
#pragma unroll
            for (int mf = 0; mf < 4; ++mf) {
                const int kb = m0 + wm * 64 + mf * 16 + kg4 * 4;
                const int bb = kb >> 12, kk = kb & (KLEN - 1);
                f16x4 pk;
#pragma unroll
                for (int rr = 0; rr < 4; ++rr) pk[rr] = (_Float16)(acc[mf][nf][rr] + bi);
                *(f16x4*)&vT[((size_t)(bb * NHEAD + (n >> 6)) * DHEAD + (n & 63)) * KLEN + kk] = pk;
            }
        }
    }
}

// -------- L1-distance attention: sad_u16 + MFMA PV (r12 EXACT, frozen) ------
// grid (NC*2, H, B) = 1024 blocks; block = 4 waves x 32 q; chunk 256 k.
__global__ __launch_bounds__(256, 4) void attn_mfma_kernel(
    const unsigned short* __restrict__ qh, const unsigned short* __restrict__ kh,
    const _Float16* __restrict__ vT, const void* __restrict__ mask,
    const float* __restrict__ rel, const int* __restrict__ mflag,
    unsigned short* __restrict__ po, float* __restrict__ ps) {
    __shared__ union SM {
        struct { unsigned short K[64][64]; _Float16 V[64][64]; _Float16 M[64]; } t;
        _Float16 osm[64][136];  // epilogue d x q transpose buffer
    } sm;
    __shared__ u32x4 qsm[4][8][32];  // [wave][16B-unit][q-row], u16 data

    const int tid = threadIdx.x;
    const int lane = tid & 63, wid = tid >> 6;
    const int l15 = lane & 15, kg4 = lane >> 4;
    const int lrow = lane >> 3, lu = lane & 7;
    const int c = blockIdx.x & (NC - 1), qhi = blockIdx.x / NC;
    const int h = blockIdx.y, b = blockIdx.z;
    const int qbase = qhi * 128 + wid * 32;
    const int mfl = *mflag;
    const float adn = rel[b * NHEAD + h];

    // stage this wave's 32 q rows: [c8][row] 16B units
#pragma unroll
    for (int s = 0; s < 2; ++s) {
        const size_t qrow = (size_t)(b * QLEN + qbase + s * 16 + l15) * EDIM + h * DHEAD;
#pragma unroll
        for (int cc = 0; cc < 2; ++cc) {
            const int c8 = kg4 * 2 + cc;
            qsm[wid][c8][s * 16 + l15] = *(const u32x4*)&qh[qrow + c8 * 8];
        }
    }
    // no barrier: each wave reads only its own qsm region (lgkm-ordered)

    f32x4 acc[2][4];
#pragma unroll
    for (int s = 0; s < 2; ++s)
#pragma unroll
        for (int nf = 0; nf < 4; ++nf) acc[s][nf] = (f32x4)0.f;
    float sacc[2] = {0.f, 0.f};

    for (int t = 0; t < (KLEN / NC) / 64; ++t) {
        const int kbase = c * (KLEN / NC) + t * 64;
        __syncthreads();  // previous tile fully consumed
#pragma unroll
        for (int i = 0; i < 2; ++i) {
            const int rb = (i * 4 + wid) * 8;
            const int krow = rb + lrow;
            const int su_k = (lu ^ (i * 4 + wid)) * 8;   // K: unit^rowgroup
            GLDS16(&kh[(size_t)(b * KLEN + kbase + krow) * EDIM + h * DHEAD + su_k],
                   &sm.t.K[rb][0]);
            const int su_v = (lu ^ lrow) * 8;            // V: unit^(d&7)
            GLDS16(&vT[(size_t)((b * NHEAD + h) * DHEAD + krow) * KLEN + kbase + su_v],
                   &sm.t.V[rb][0]);
        }
        if (tid < 64) {
            const int kg = b * KLEN + kbase + tid;
            const int mv = mfl ? ((const int*)mask)[kg]
                               : (int)((const unsigned char*)mask)[kg];
            sm.t.M[tid] = mv ? (_Float16)1.f : (_Float16)0.f;
        }
        __syncthreads();  // drains glds (vmcnt) + mask writes

        unsigned dist[2][16];
#pragma unroll
        for (int s = 0; s < 2; ++s)
#pragma unroll
            for (int j = 0; j < 16; ++j) dist[s][j] = 0u;

#pragma unroll
        for (int c8 = 0; c8 < 8; ++c8) {
            u32x4 qv[2];
            qv[0] = qsm[wid][c8][l15];
            qv[1] = qsm[wid][c8][16 + l15];
#pragma unroll
            for (int hf = 0; hf < 2; ++hf) {
                const int unit = (c8 ^ (hf * 4 + kg4)) * 8;
#pragma unroll
                for (int j = 0; j < 8; ++j) {
                    const int kk = hf * 32 + kg4 * 8 + j;
                    const u32x4 ku = *(const u32x4*)&sm.t.K[kk][unit];
#pragma unroll
                    for (int p = 0; p < 4; ++p) {
                        dist[0][hf * 8 + j] = __builtin_amdgcn_sad_u16(
                            ku[p], qv[0][p], dist[0][hf * 8 + j]);
                        dist[1][hf * 8 + j] = __builtin_amdgcn_sad_u16(
                            ku[p], qv[1][p], dist[1][hf * 8 + j]);
                    }
                }
            }
        }

#pragma unroll
        for (int hf = 0; hf < 2; ++hf) {
            const f16x8 mv8 = *(const f16x8*)&sm.t.M[hf * 32 + kg4 * 8];
            unsigned pw[2][4];
#pragma unroll
            for (int s = 0; s < 2; ++s) {
                float w[8];
#pragma unroll
                for (int j = 0; j < 8; ++j) {
                    // e = mask * 2^(C2 - dist*s); w = e/(e+adn)  (== reference)
                    const float e =
                        exp2f(C2EXP - (float)dist[s][hf * 8 + j] * SADSCALE) * (float)mv8[j];
                    w[j] = e * __builtin_amdgcn_rcpf(e + adn);
                    sacc[s] += w[j];
                }
#pragma unroll
                for (int m2 = 0; m2 < 4; ++m2)
                    pw[s][m2] = __builtin_bit_cast(unsigned,
                        __builtin_amdgcn_cvt_pkrtz(w[2 * m2], w[2 * m2 + 1]));
            }
#pragma unroll
            for (int nf = 0; nf < 4; ++nf) {
                const int vrow = nf * 16 + l15;
                const f16x8 b8 = *(const f16x8*)
                    &sm.t.V[vrow][(((hf * 4 + kg4) ^ (l15 & 7))) * 8];
                union { unsigned u[4]; f16x8 v; } a0, a1;
#pragma unroll
                for (int p = 0; p < 4; ++p) { a0.u[p] = pw[0][p]; a1.u[p] = pw[1][p]; }
                acc[0][nf] = __builtin_amdgcn_mfma_f32_16x16x32_f16(a0.v, b8, acc[0][nf], 0, 0, 0);
                acc[1][nf] = __builtin_amdgcn_mfma_f32_16x16x32_f16(a1.v, b8, acc[1][nf], 0, 0, 0);
            }
        }
    }

#pragma unroll
    for (int s = 0; s < 2; ++s) {
        sacc[s] += __shfl_xor(sacc[s], 16);
        sacc[s] += __shfl_xor(sacc[s], 32);
    }
    const size_t bhc = (size_t)(b * NHEAD + h) * NC + c;
    if (lane < 16) {
#pragma unroll
        for (int s = 0; s < 2; ++s)
            ps[bhc * QLEN + qbase + s * 16 + lane] = sacc[s];
    }

    __syncthreads();  // everyone done with sm.t
#pragma unroll
    for (int s = 0; s < 2; ++s)
#pragma unroll
        for (int nf = 0; nf < 4; ++nf)
#pragma unroll
            for (int rr = 0; rr < 4; ++rr) {
                const int qloc = wid * 32 + s * 16 + kg4 * 4 + rr;
                sm.osm[nf * 16 + l15][qloc] = (_Float16)acc[s][nf][rr];
            }
    __syncthreads();
    {
        const int d = tid >> 2, seg = tid & 3;
        const f16x8* src = (const f16x8*)&sm.osm[d][seg * 32];
        f16x8* dst = (f16x8*)(po + (bhc * 64 + d) * QLEN + qhi * 128 + seg * 32);
#pragma unroll
        for (int i = 0; i < 4; ++i) dst[i] = src[i];
    }
}

// -------- combine partials, normalize, write out ----------------------------
__global__ __launch_bounds__(256) void combine_kernel(
    const unsigned short* __restrict__ po, const float* __restrict__ ps,
    float* __restrict__ out, int nch) {
    const int d4 = blockIdx.x, h = blockIdx.y, b = blockIdx.z;
    const int q = threadIdx.x;
    const int bh = b * NHEAD + h;

    float s = 0.f;
    for (int c = 0; c < nch; ++c)
        s += ps[((size_t)(bh * nch + c)) * QLEN + q];

    float o[4] = {0.f, 0.f, 0.f, 0.f};
    for (int c = 0; c < nch; ++c) {
#pragma unroll
        for (int j = 0; j < 4; ++j) {
            const int d = d4 * 4 + j;
            const unsigned short raw = po[((size_t)((bh * nch + c) * 64 + d)) * QLEN + q];
            o[j] += (float)*(const _Float16*)&raw;
        }
    }
    const float inv = 1.0f / fmaxf(s, 1e-12f);
#pragma unroll
    for (int j = 0; j < 4; ++j)
        out[((size_t)(b * QLEN + q)) * EDIM + h * DHEAD + d4 * 4 + j] = o[j] * inv;
}

extern "C" void kernel_launch(void* const* d_in, const int* in_sizes, int n_in,
                              void* d_out, int out_size, void* d_ws, size_t ws_size,
                              hipStream_t stream) {
    const float* query = (const float*)d_in[0];
    const float* bag   = (const float*)d_in[1];
    const void*  mask  = d_in[2];
    const float* rel   = (const float*)d_in[3];
    const float* Wqk   = (const float*)d_in[4];
    const float* bqk   = (const float*)d_in[5];
    const float* Wv    = (const float*)d_in[6];
    const float* bv    = (const float*)d_in[7];
    const float* diag  = (const float*)d_in[8];
    float* out = (float*)d_out;

    char* wsb = (char*)d_ws;
    int* mflag = (int*)wsb;
    unsigned short* qh = (unsigned short*)(wsb + 16);
    unsigned short* kh = qh + (size_t)BATCH * QLEN * EDIM;
    _Float16* vT = (_Float16*)(kh + (size_t)BATCH * KLEN * EDIM);
    char* region = (char*)(vT + (size_t)BATCH * KLEN * EDIM);
    // phase 1 (pre-attn)
    _Float16* bag_h = (_Float16*)region;
    _Float16* wqk_h = bag_h + (size_t)BATCH * KLEN * EDIM;
    _Float16* wv_h = wqk_h + (size_t)EDIM * EDIM;
    _Float16* query_h = wv_h + (size_t)EDIM * EDIM;
    // phase 2 (attn output partials) — overlaps phase 1 (order-safe)
    unsigned short* po = (unsigned short*)region;
    float* psb = (float*)(region + (size_t)BATCH * NHEAD * NC * QLEN * DHEAD * 2);

    convert_kernel<<<2048, 256, 0, stream>>>(
        bag, Wqk, Wv, query, (const unsigned char*)mask,
        bag_h, wqk_h, wv_h, query_h, mflag);

    // unified GEMM (8-wave, 64x32 wave-tile): k'/q' = quant_u16((X@Wqk^T+bqk)
    // *diag*alpha); v -> vT.  grid (136,8): same-A blocks share an XCD.
    proj_gemm_kernel<<<dim3(136, 8), 512, 0, stream>>>(
        bag_h, query_h, wqk_h, wv_h, bqk, bv, diag, kh, qh, vT);

    attn_mfma_kernel<<<dim3(NC * 2, NHEAD, BATCH), 256, 0, stream>>>(
        qh, kh, vT, mask, rel, mflag, po, psb);

    combine_kernel<<<dim3(16, NHEAD, BATCH), 256, 0, stream>>>(po, psb, out, NC);
}

// Round 17
// 139.688 us; speedup vs baseline: 1.0558x; 1.0019x over previous
//
#include <hip/hip_runtime.h>

// CAPBlock r17: r16 (140.0us best) with ONE change — proj double-buffered
// (Ah[2]/Bh[2] = 64KB LDS; stage(t+1) issued before compute(t), ONE barrier
// per step, 8 barriers vs 16). Residency unchanged (VGPR-capped 2 blocks/CU);
// stage latency now hidden in-block. 8-wave 64x32 wave-tile kept (r16's win).
// convert/attn/combine BYTE-IDENTICAL to r16 (attn frozen at 67.3us).
// Shapes: B=4, Q=256, K=4096, Ein=E=512, H=8, DH=64.
//
// ws (53.4MB):
//   mflag 16B | qh u16 1MB | kh u16 16.8MB | vT f16 16.8MB | REGION 18.8MB
//   REGION phase1: bag_h 16.8 | wqk_h 0.5 | wv_h 0.5 | query_h 1.0
//   REGION phase2: po 16.8 | ps 0.5

#define BATCH 4
#define QLEN 256
#define KLEN 4096
#define EDIM 512
#define NHEAD 8
#define DHEAD 64
#define NC 16

#define ALPHA 0.21153831f
#define C2EXP 15.276518f
#define QSCALE 16384.0f
#define SADSCALE 6.103515625e-5f  // 1/16384

typedef float f32x4 __attribute__((ext_vector_type(4)));
typedef _Float16 f16x8 __attribute__((ext_vector_type(8)));
typedef _Float16 f16x4 __attribute__((ext_vector_type(4)));
typedef unsigned int u32x4 __attribute__((ext_vector_type(4)));

#define GLDS16(g, l)                                                     \
    __builtin_amdgcn_global_load_lds(                                    \
        (const __attribute__((address_space(1))) unsigned int*)(g),      \
        (__attribute__((address_space(3))) unsigned int*)(l), 16, 0, 0)

__device__ __forceinline__ unsigned short quant_u16(float x) {
    const float y = fminf(fmaxf(x * QSCALE + 32768.5f, 0.f), 65535.f);
    return (unsigned short)y;
}

// -------- f32 -> fp16 convert (bag, Wqk, Wv, query) + mask detect -----------
__global__ __launch_bounds__(256) void convert_kernel(
    const float* __restrict__ bag, const float* __restrict__ wqk,
    const float* __restrict__ wv, const float* __restrict__ query,
    const unsigned char* __restrict__ mask,
    _Float16* __restrict__ bag_h, _Float16* __restrict__ wqk_h,
    _Float16* __restrict__ wv_h, _Float16* __restrict__ query_h,
    int* __restrict__ flag) {
    const int NB = (BATCH * KLEN * EDIM) / 4;   // float4 counts
    const int NW = (EDIM * EDIM) / 4;
    const int NQ = (BATCH * QLEN * EDIM) / 4;
    for (int i = blockIdx.x * 256 + threadIdx.x; i < NB + 2 * NW + NQ;
         i += gridDim.x * 256) {
        const float4* s;
        _Float16* d;
        int j;
        if (i < NB) { s = (const float4*)bag; d = bag_h; j = i; }
        else if (i < NB + NW) { s = (const float4*)wqk; d = wqk_h; j = i - NB; }
        else if (i < NB + 2 * NW) { s = (const float4*)wv; d = wv_h; j = i - NB - NW; }
        else { s = (const float4*)query; d = query_h; j = i - NB - 2 * NW; }
        const float4 v = s[j];
        f16x4 h;
        h[0] = (_Float16)v.x; h[1] = (_Float16)v.y;
        h[2] = (_Float16)v.z; h[3] = (_Float16)v.w;
        *(f16x4*)&d[(size_t)j * 4] = h;
    }
    // mask dtype detect (bool-as-byte vs int32); deterministic per input.
    if (blockIdx.x == 0) {
        __shared__ int nz;
        if (threadIdx.x == 0) nz = 0;
        __syncthreads();
        int acc = 0;
        for (int i = threadIdx.x; i < BATCH * KLEN; i += 256)
            if (i & 3) acc |= mask[i];
        if (acc) atomicOr(&nz, 1);
        __syncthreads();
        if (threadIdx.x == 0) *flag = (nz == 0) ? 1 : 0;  // 1 => int32
    }
}

// -------- unified projection GEMM: 8-wave 64x32 wave-tile, DBUF glds --------
// grid (136, 8): by = A m-tile (XCD = by%8 -> same-A blocks share an XCD L2),
// bx = n-path (<4: Wqk -> kh/qh, >=4: Wv -> vT). 512 thr = 8 waves (2m x 4n),
// acc[4][2] (32 regs). Double-buffered BK=64: stage(t+1) issued BEFORE
// compute(t); one __syncthreads per step (vmcnt0+lgkm0+barrier drain).
__global__ __launch_bounds__(512) void proj_gemm_kernel(
    const _Float16* __restrict__ bag_h, const _Float16* __restrict__ query_h,
    const _Float16* __restrict__ wqk_h, const _Float16* __restrict__ wv_h,
    const float* __restrict__ bqk, const float* __restrict__ bv,
    const float* __restrict__ diag, unsigned short* __restrict__ kh,
    unsigned short* __restrict__ qh, _Float16* __restrict__ vT) {
    __shared__ _Float16 Ah[2][128][64];
    __shared__ _Float16 Bh[2][128][64];

    const int tid = threadIdx.x;
    const int lane = tid & 63, wid = tid >> 6;      // 8 waves
    const int wm = wid >> 2, wn = wid & 3;          // 2m x 4n
    const int l15 = lane & 15, kg4 = lane >> 4;
    const int lrow = lane >> 3, lu = lane & 7;
    const int by = blockIdx.x;         // A m-tile (XCD-locality axis)
    const int bx = blockIdx.y;         // n-path
    const int isV = bx >> 2;
    const int isQ = by >> 7;           // query m-tiles (Wqk path only)
    if (isV && isQ) return;            // uniform across block: safe
    const _Float16* __restrict__ W = isV ? wv_h : wqk_h;
    const _Float16* __restrict__ A = isQ ? query_h : bag_h;
    const int n0 = (bx & 3) * 128;
    const int m0 = (isQ ? (by - 128) : by) * 128;  // local to A buffer
    const int srcu = (lu ^ lrow) * 8;  // pre-swizzled source unit (halves)

    f32x4 acc[4][2];
#pragma unroll
    for (int i = 0; i < 4; ++i)
#pragma unroll
        for (int j = 0; j < 2; ++j) acc[i][j] = (f32x4)0.f;

    // prologue: stage tile 0 into buffer 0 (each wave: 8 rows x 8 units x2)
#pragma unroll
    for (int i = 0; i < 2; ++i) {
        const int rb = i * 64 + wid * 8;
        const int row = rb + lrow;
        GLDS16(&A[(size_t)(m0 + row) * EDIM + srcu], &Ah[0][rb][0]);
        GLDS16(&W[(size_t)(n0 + row) * EDIM + srcu], &Bh[0][rb][0]);
    }
    __syncthreads();  // vmcnt(0) drain + barrier

    for (int t = 0; t < 8; ++t) {
        const int cur = t & 1;
        if (t < 7) {  // issue next tile's stage FIRST (hides under compute)
            const int k1 = (t + 1) * 64;
#pragma unroll
            for (int i = 0; i < 2; ++i) {
                const int rb = i * 64 + wid * 8;
                const int row = rb + lrow;
                GLDS16(&A[(size_t)(m0 + row) * EDIM + k1 + srcu],
                       &Ah[cur ^ 1][rb][0]);
                GLDS16(&W[(size_t)(n0 + row) * EDIM + k1 + srcu],
                       &Bh[cur ^ 1][rb][0]);
            }
        }
        // compute current tile
#pragma unroll
        for (int s = 0; s < 2; ++s) {
            f16x8 a8[4], b8[2];
#pragma unroll
            for (int mf = 0; mf < 4; ++mf) {
                const int row = wm * 64 + mf * 16 + l15;
                a8[mf] = *(const f16x8*)&Ah[cur][row][((s * 4 + kg4) ^ (row & 7)) * 8];
            }
#pragma unroll
            for (int nf = 0; nf < 2; ++nf) {
                const int row = wn * 32 + nf * 16 + l15;
                b8[nf] = *(const f16x8*)&Bh[cur][row][((s * 4 + kg4) ^ (row & 7)) * 8];
            }
#pragma unroll
            for (int nf = 0; nf < 2; ++nf)
#pragma unroll
                for (int mf = 0; mf < 4; ++mf)
                    acc[mf][nf] = __builtin_amdgcn_mfma_f32_16x16x32_f16(
                        a8[mf], b8[nf], acc[mf][nf], 0, 0, 0);
        }
        __syncthreads();  // drains next-tile glds + orders buffer reuse
    }

#pragma unroll
    for (int nf = 0; nf < 2; ++nf) {
        const int n = n0 + wn * 32 + nf * 16 + l15;
        if (!isV) {
            const float bi = bqk[n];
            const float sc = diag[n] * ALPHA;
            unsigned short* __restrict__ dst = isQ ? qh : kh;
#pragma unroll
            for (int mf = 0; mf < 4; ++mf)
#pragma unroll
                for (int rr = 0; rr < 4; ++rr) {
                    const int m = m0 + wm * 64 + mf * 16 + kg4 * 4 + rr;
                    dst[(size_t)m * EDIM + n] = quant_u16((acc[mf][nf][rr] + bi) * sc);
                }
        } else {
            const float bi = bv[n];
#pragma unroll
            for (int mf = 0; mf < 4; ++mf) {
                const int kb = m0 + wm * 64 + mf * 16 + kg4 * 4;
                const int bb = kb >> 12, kk = kb & (KLEN - 1);
                f16x4 pk;
#pragma unroll
                for (int rr = 0; rr < 4; ++rr) pk[rr] = (_Float16)(acc[mf][nf][rr] + bi);
                *(f16x4*)&vT[((size_t)(bb * NHEAD + (n >> 6)) * DHEAD + (n & 63)) * KLEN + kk] = pk;
            }
        }
    }
}

// -------- L1-distance attention: sad_u16 + MFMA PV (r12 EXACT, frozen) ------
// grid (NC*2, H, B) = 1024 blocks; block = 4 waves x 32 q; chunk 256 k.
__global__ __launch_bounds__(256, 4) void attn_mfma_kernel(
    const unsigned short* __restrict__ qh, const unsigned short* __restrict__ kh,
    const _Float16* __restrict__ vT, const void* __restrict__ mask,
    const float* __restrict__ rel, const int* __restrict__ mflag,
    unsigned short* __restrict__ po, float* __restrict__ ps) {
    __shared__ union SM {
        struct { unsigned short K[64][64]; _Float16 V[64][64]; _Float16 M[64]; } t;
        _Float16 osm[64][136];  // epilogue d x q transpose buffer
    } sm;
    __shared__ u32x4 qsm[4][8][32];  // [wave][16B-unit][q-row], u16 data

    const int tid = threadIdx.x;
    const int lane = tid & 63, wid = tid >> 6;
    const int l15 = lane & 15, kg4 = lane >> 4;
    const int lrow = lane >> 3, lu = lane & 7;
    const int c = blockIdx.x & (NC - 1), qhi = blockIdx.x / NC;
    const int h = blockIdx.y, b = blockIdx.z;
    const int qbase = qhi * 128 + wid * 32;
    const int mfl = *mflag;
    const float adn = rel[b * NHEAD + h];

    // stage this wave's 32 q rows: [c8][row] 16B units
#pragma unroll
    for (int s = 0; s < 2; ++s) {
        const size_t qrow = (size_t)(b * QLEN + qbase + s * 16 + l15) * EDIM + h * DHEAD;
#pragma unroll
        for (int cc = 0; cc < 2; ++cc) {
            const int c8 = kg4 * 2 + cc;
            qsm[wid][c8][s * 16 + l15] = *(const u32x4*)&qh[qrow + c8 * 8];
        }
    }
    // no barrier: each wave reads only its own qsm region (lgkm-ordered)

    f32x4 acc[2][4];
#pragma unroll
    for (int s = 0; s < 2; ++s)
#pragma unroll
        for (int nf = 0; nf < 4; ++nf) acc[s][nf] = (f32x4)0.f;
    float sacc[2] = {0.f, 0.f};

    for (int t = 0; t < (KLEN / NC) / 64; ++t) {
        const int kbase = c * (KLEN / NC) + t * 64;
        __syncthreads();  // previous tile fully consumed
#pragma unroll
        for (int i = 0; i < 2; ++i) {
            const int rb = (i * 4 + wid) * 8;
            const int krow = rb + lrow;
            const int su_k = (lu ^ (i * 4 + wid)) * 8;   // K: unit^rowgroup
            GLDS16(&kh[(size_t)(b * KLEN + kbase + krow) * EDIM + h * DHEAD + su_k],
                   &sm.t.K[rb][0]);
            const int su_v = (lu ^ lrow) * 8;            // V: unit^(d&7)
            GLDS16(&vT[(size_t)((b * NHEAD + h) * DHEAD + krow) * KLEN + kbase + su_v],
                   &sm.t.V[rb][0]);
        }
        if (tid < 64) {
            const int kg = b * KLEN + kbase + tid;
            const int mv = mfl ? ((const int*)mask)[kg]
                               : (int)((const unsigned char*)mask)[kg];
            sm.t.M[tid] = mv ? (_Float16)1.f : (_Float16)0.f;
        }
        __syncthreads();  // drains glds (vmcnt) + mask writes

        unsigned dist[2][16];
#pragma unroll
        for (int s = 0; s < 2; ++s)
#pragma unroll
            for (int j = 0; j < 16; ++j) dist[s][j] = 0u;

#pragma unroll
        for (int c8 = 0; c8 < 8; ++c8) {
            u32x4 qv[2];
            qv[0] = qsm[wid][c8][l15];
            qv[1] = qsm[wid][c8][16 + l15];
#pragma unroll
            for (int hf = 0; hf < 2; ++hf) {
                const int unit = (c8 ^ (hf * 4 + kg4)) * 8;
#pragma unroll
                for (int j = 0; j < 8; ++j) {
                    const int kk = hf * 32 + kg4 * 8 + j;
                    const u32x4 ku = *(const u32x4*)&sm.t.K[kk][unit];
#pragma unroll
                    for (int p = 0; p < 4; ++p) {
                        dist[0][hf * 8 + j] = __builtin_amdgcn_sad_u16(
                            ku[p], qv[0][p], dist[0][hf * 8 + j]);
                        dist[1][hf * 8 + j] = __builtin_amdgcn_sad_u16(
                            ku[p], qv[1][p], dist[1][hf * 8 + j]);
                    }
                }
            }
        }

#pragma unroll
        for (int hf = 0; hf < 2; ++hf) {
            const f16x8 mv8 = *(const f16x8*)&sm.t.M[hf * 32 + kg4 * 8];
            unsigned pw[2][4];
#pragma unroll
            for (int s = 0; s < 2; ++s) {
                float w[8];
#pragma unroll
                for (int j = 0; j < 8; ++j) {
                    // e = mask * 2^(C2 - dist*s); w = e/(e+adn)  (== reference)
                    const float e =
                        exp2f(C2EXP - (float)dist[s][hf * 8 + j] * SADSCALE) * (float)mv8[j];
                    w[j] = e * __builtin_amdgcn_rcpf(e + adn);
                    sacc[s] += w[j];
                }
#pragma unroll
                for (int m2 = 0; m2 < 4; ++m2)
                    pw[s][m2] = __builtin_bit_cast(unsigned,
                        __builtin_amdgcn_cvt_pkrtz(w[2 * m2], w[2 * m2 + 1]));
            }
#pragma unroll
            for (int nf = 0; nf < 4; ++nf) {
                const int vrow = nf * 16 + l15;
                const f16x8 b8 = *(const f16x8*)
                    &sm.t.V[vrow][(((hf * 4 + kg4) ^ (l15 & 7))) * 8];
                union { unsigned u[4]; f16x8 v; } a0, a1;
#pragma unroll
                for (int p = 0; p < 4; ++p) { a0.u[p] = pw[0][p]; a1.u[p] = pw[1][p]; }
                acc[0][nf] = __builtin_amdgcn_mfma_f32_16x16x32_f16(a0.v, b8, acc[0][nf], 0, 0, 0);
                acc[1][nf] = __builtin_amdgcn_mfma_f32_16x16x32_f16(a1.v, b8, acc[1][nf], 0, 0, 0);
            }
        }
    }

#pragma unroll
    for (int s = 0; s < 2; ++s) {
        sacc[s] += __shfl_xor(sacc[s], 16);
        sacc[s] += __shfl_xor(sacc[s], 32);
    }
    const size_t bhc = (size_t)(b * NHEAD + h) * NC + c;
    if (lane < 16) {
#pragma unroll
        for (int s = 0; s < 2; ++s)
            ps[bhc * QLEN + qbase + s * 16 + lane] = sacc[s];
    }

    __syncthreads();  // everyone done with sm.t
#pragma unroll
    for (int s = 0; s < 2; ++s)
#pragma unroll
        for (int nf = 0; nf < 4; ++nf)
#pragma unroll
            for (int rr = 0; rr < 4; ++rr) {
                const int qloc = wid * 32 + s * 16 + kg4 * 4 + rr;
                sm.osm[nf * 16 + l15][qloc] = (_Float16)acc[s][nf][rr];
            }
    __syncthreads();
    {
        const int d = tid >> 2, seg = tid & 3;
        const f16x8* src = (const f16x8*)&sm.osm[d][seg * 32];
        f16x8* dst = (f16x8*)(po + (bhc * 64 + d) * QLEN + qhi * 128 + seg * 32);
#pragma unroll
        for (int i = 0; i < 4; ++i) dst[i] = src[i];
    }
}

// -------- combine partials, normalize, write out ----------------------------
__global__ __launch_bounds__(256) void combine_kernel(
    const unsigned short* __restrict__ po, const float* __restrict__ ps,
    float* __restrict__ out, int nch) {
    const int d4 = blockIdx.x, h = blockIdx.y, b = blockIdx.z;
    const int q = threadIdx.x;
    const int bh = b * NHEAD + h;

    float s = 0.f;
    for (int c = 0; c < nch; ++c)
        s += ps[((size_t)(bh * nch + c)) * QLEN + q];

    float o[4] = {0.f, 0.f, 0.f, 0.f};
    for (int c = 0; c < nch; ++c) {
#pragma unroll
        for (int j = 0; j < 4; ++j) {
            const int d = d4 * 4 + j;
            const unsigned short raw = po[((size_t)((bh * nch + c) * 64 + d)) * QLEN + q];
            o[j] += (float)*(const _Float16*)&raw;
        }
    }
    const float inv = 1.0f / fmaxf(s, 1e-12f);
#pragma unroll
    for (int j = 0; j < 4; ++j)
        out[((size_t)(b * QLEN + q)) * EDIM + h * DHEAD + d4 * 4 + j] = o[j] * inv;
}

extern "C" void kernel_launch(void* const* d_in, const int* in_sizes, int n_in,
                              void* d_out, int out_size, void* d_ws, size_t ws_size,
                              hipStream_t stream) {
    const float* query = (const float*)d_in[0];
    const float* bag   = (const float*)d_in[1];
    const void*  mask  = d_in[2];
    const float* rel   = (const float*)d_in[3];
    const float* Wqk   = (const float*)d_in[4];
    const float* bqk   = (const float*)d_in[5];
    const float* Wv    = (const float*)d_in[6];
    const float* bv    = (const float*)d_in[7];
    const float* diag  = (const float*)d_in[8];
    float* out = (float*)d_out;

    char* wsb = (char*)d_ws;
    int* mflag = (int*)wsb;
    unsigned short* qh = (unsigned short*)(wsb + 16);
    unsigned short* kh = qh + (size_t)BATCH * QLEN * EDIM;
    _Float16* vT = (_Float16*)(kh + (size_t)BATCH * KLEN * EDIM);
    char* region = (char*)(vT + (size_t)BATCH * KLEN * EDIM);
    // phase 1 (pre-attn)
    _Float16* bag_h = (_Float16*)region;
    _Float16* wqk_h = bag_h + (size_t)BATCH * KLEN * EDIM;
    _Float16* wv_h = wqk_h + (size_t)EDIM * EDIM;
    _Float16* query_h = wv_h + (size_t)EDIM * EDIM;
    // phase 2 (attn output partials) — overlaps phase 1 (order-safe)
    unsigned short* po = (unsigned short*)region;
    float* psb = (float*)(region + (size_t)BATCH * NHEAD * NC * QLEN * DHEAD * 2);

    convert_kernel<<<2048, 256, 0, stream>>>(
        bag, Wqk, Wv, query, (const unsigned char*)mask,
        bag_h, wqk_h, wv_h, query_h, mflag);

    // unified dbuf GEMM (8-wave, 64x32 wave-tile): k'/q' = quant_u16(
    // (X@Wqk^T+bqk)*diag*alpha); v -> vT.  grid (136,8): A-tile shares an XCD.
    proj_gemm_kernel<<<dim3(136, 8), 512, 0, stream>>>(
        bag_h, query_h, wqk_h, wv_h, bqk, bv, diag, kh, qh, vT);

    attn_mfma_kernel<<<dim3(NC * 2, NHEAD, BATCH), 256, 0, stream>>>(
        qh, kh, vT, mask, rel, mflag, po, psb);

    combine_kernel<<<dim3(16, NHEAD, BATCH), 256, 0, stream>>>(po, psb, out, NC);
}